// Round 1
// baseline (654.277 us; speedup 1.0000x reference)
//
#include <hip/hip_runtime.h>
#include <hip/hip_bf16.h>

#define BB 2
#define NN 65536
#define DP 64
#define DM 128
#define SCALEF 0.08838834764831845f   // 1/sqrt(128)

// ---------- helpers ----------
__device__ __forceinline__ unsigned fenc(float f) {
  unsigned u = __float_as_uint(f);
  return (u & 0x80000000u) ? ~u : (u | 0x80000000u);   // order-preserving float->uint
}
__device__ __forceinline__ float fdec(unsigned u) {
  unsigned v = (u & 0x80000000u) ? (u & 0x7FFFFFFFu) : ~u;
  return __uint_as_float(v);
}
__device__ __forceinline__ unsigned short f2bf(float f) {   // round-to-nearest-even bf16
  unsigned u = __float_as_uint(f);
  u += 0x7FFFu + ((u >> 16) & 1u);
  return (unsigned short)(u >> 16);
}
__device__ __forceinline__ float bf2f(unsigned short h) {
  return __uint_as_float(((unsigned)h) << 16);
}

// OUT[64][128] += A[64][K] @ W[K][128]; A in LDS (row stride LDA), W global, staged
// through Ws (32x128). Thread (tm,tn) owns points tm*8..tm*8+7, channels tn*4..tn*4+3.
template<int K, int LDA>
__device__ __forceinline__ void mm_tile(const float* __restrict__ As,
                                        const float* __restrict__ Wg,
                                        float* __restrict__ Ws,
                                        int tid, int pbase, int c4,
                                        float acc[8][4]) {
  for (int k0 = 0; k0 < K; k0 += 32) {
    __syncthreads();                       // prior readers of Ws / writers of As done
    {
      const float4* wgl = (const float4*)(Wg + k0 * DM);
      float4* wsl = (float4*)Ws;
#pragma unroll
      for (int j = 0; j < 4; ++j) wsl[tid + j * 256] = wgl[tid + j * 256];
    }
    __syncthreads();
#pragma unroll
    for (int kk = 0; kk < 32; kk += 4) {
      float4 a4[8];
#pragma unroll
      for (int p = 0; p < 8; ++p)
        a4[p] = *(const float4*)(As + (pbase + p) * LDA + (k0 + kk));
#pragma unroll
      for (int i = 0; i < 4; ++i) {
        float4 w4 = *(const float4*)(Ws + (kk + i) * DM + c4);
#pragma unroll
        for (int p = 0; p < 8; ++p) {
          float a = (i == 0) ? a4[p].x : (i == 1) ? a4[p].y : (i == 2) ? a4[p].z : a4[p].w;
          acc[p][0] = fmaf(a, w4.x, acc[p][0]);
          acc[p][1] = fmaf(a, w4.y, acc[p][1]);
          acc[p][2] = fmaf(a, w4.z, acc[p][2]);
          acc[p][3] = fmaf(a, w4.w, acc[p][3]);
        }
      }
    }
  }
}

// ---------- K0: wqk = wq - wk, zero sums/maxenc ----------
__global__ __launch_bounds__(256) void k0_kernel(const float* __restrict__ wq,
                                                 const float* __restrict__ wk,
                                                 float* __restrict__ wqk,
                                                 float* __restrict__ zbuf) {
  int i = blockIdx.x * 256 + threadIdx.x;
  if (i < 512) zbuf[i] = 0.0f;             // sums[256] + maxenc[256]
  if (i < DM * DM) wqk[i] = wq[i] - wk[i];
}

// ---------- K1: chain up to logits + G ----------
__global__ __launch_bounds__(256) void k1_kernel(
    const float* __restrict__ xyz, const float* __restrict__ features,
    const float* __restrict__ fc1_w, const float* __restrict__ fc1_b,
    const float* __restrict__ d1_w, const float* __restrict__ d1_b,
    const float* __restrict__ d2_w, const float* __restrict__ d2_b,
    const float* __restrict__ g1_w, const float* __restrict__ g1_b,
    const float* __restrict__ g2_w, const float* __restrict__ g2_b,
    const float* __restrict__ wqk, const float* __restrict__ wv_w,
    float* __restrict__ out_logits, unsigned short* __restrict__ Gbf,
    unsigned* __restrict__ maxenc) {
  __shared__ float As[64 * DM];   // R -> F -> T -> H
  __shared__ float Xs[64 * DM];   // X (persists)
  __shared__ float Ws[32 * DM];   // weight chunks; also xyz tile, max-reduce buf

  const int tid = threadIdx.x;
  const int tn = tid & 31, tm = tid >> 5;
  const int c4 = tn * 4, pbase = tm * 8;
  const long long p0 = (long long)blockIdx.x * 64;
  const int b = (int)(p0 >> 16);

  if (tid < 192) Ws[tid] = xyz[p0 * 3 + tid];

  float4 d1w0 = *(const float4*)(d1_w + 0 * DM + c4);
  float4 d1w1 = *(const float4*)(d1_w + 1 * DM + c4);
  float4 d1w2 = *(const float4*)(d1_w + 2 * DM + c4);
  float4 d1bb = *(const float4*)(d1_b + c4);
  __syncthreads();
#pragma unroll
  for (int p = 0; p < 8; ++p) {
    float x0 = Ws[(pbase + p) * 3 + 0];
    float x1 = Ws[(pbase + p) * 3 + 1];
    float x2 = Ws[(pbase + p) * 3 + 2];
    float4 r;
    r.x = fmaxf(0.f, fmaf(x0, d1w0.x, fmaf(x1, d1w1.x, fmaf(x2, d1w2.x, d1bb.x))));
    r.y = fmaxf(0.f, fmaf(x0, d1w0.y, fmaf(x1, d1w1.y, fmaf(x2, d1w2.y, d1bb.y))));
    r.z = fmaxf(0.f, fmaf(x0, d1w0.z, fmaf(x1, d1w1.z, fmaf(x2, d1w2.z, d1bb.z))));
    r.w = fmaxf(0.f, fmaf(x0, d1w0.w, fmaf(x1, d1w1.w, fmaf(x2, d1w2.w, d1bb.w))));
    *(float4*)(As + (pbase + p) * DM + c4) = r;
  }

  float acc[8][4], pe[8][4];
#pragma unroll
  for (int p = 0; p < 8; ++p)
    acc[p][0] = acc[p][1] = acc[p][2] = acc[p][3] = 0.f;

  // PE = R @ d2 + d2_b  (kept in regs)
  mm_tile<DM, DM>(As, d2_w, Ws, tid, pbase, c4, acc);
  {
    float4 bb = *(const float4*)(d2_b + c4);
#pragma unroll
    for (int p = 0; p < 8; ++p) {
      pe[p][0] = acc[p][0] + bb.x; pe[p][1] = acc[p][1] + bb.y;
      pe[p][2] = acc[p][2] + bb.z; pe[p][3] = acc[p][3] + bb.w;
    }
  }

  // F -> As (64x64)
  __syncthreads();
  {
    const float4* Fg = (const float4*)(features + p0 * DP);
    float4* Fl = (float4*)As;
#pragma unroll
    for (int j = 0; j < 4; ++j) Fl[tid + j * 256] = Fg[tid + j * 256];
  }
#pragma unroll
  for (int p = 0; p < 8; ++p)
    acc[p][0] = acc[p][1] = acc[p][2] = acc[p][3] = 0.f;
  // X = F @ fc1 + fc1_b -> Xs
  mm_tile<DP, DP>(As, fc1_w, Ws, tid, pbase, c4, acc);
  {
    float4 bb = *(const float4*)(fc1_b + c4);
#pragma unroll
    for (int p = 0; p < 8; ++p) {
      float4 v;
      v.x = acc[p][0] + bb.x; v.y = acc[p][1] + bb.y;
      v.z = acc[p][2] + bb.z; v.w = acc[p][3] + bb.w;
      *(float4*)(Xs + (pbase + p) * DM + c4) = v;
    }
  }

  // T = PE + X @ wqk  -> As   (wqk mm's internal barriers separate fc1's As readers)
#pragma unroll
  for (int p = 0; p < 8; ++p) {
    acc[p][0] = pe[p][0]; acc[p][1] = pe[p][1];
    acc[p][2] = pe[p][2]; acc[p][3] = pe[p][3];
  }
  mm_tile<DM, DM>(Xs, wqk, Ws, tid, pbase, c4, acc);
  __syncthreads();
#pragma unroll
  for (int p = 0; p < 8; ++p) {
    float4 v; v.x = acc[p][0]; v.y = acc[p][1]; v.z = acc[p][2]; v.w = acc[p][3];
    *(float4*)(As + (pbase + p) * DM + c4) = v;
  }

  // H = relu(T @ g1 + g1_b) -> As
#pragma unroll
  for (int p = 0; p < 8; ++p)
    acc[p][0] = acc[p][1] = acc[p][2] = acc[p][3] = 0.f;
  mm_tile<DM, DM>(As, g1_w, Ws, tid, pbase, c4, acc);
  {
    float4 bb = *(const float4*)(g1_b + c4);
    __syncthreads();
#pragma unroll
    for (int p = 0; p < 8; ++p) {
      float4 v;
      v.x = fmaxf(0.f, acc[p][0] + bb.x); v.y = fmaxf(0.f, acc[p][1] + bb.y);
      v.z = fmaxf(0.f, acc[p][2] + bb.z); v.w = fmaxf(0.f, acc[p][3] + bb.w);
      *(float4*)(As + (pbase + p) * DM + c4) = v;
    }
  }

  // L = H @ g2 + g2_b -> global logits (attn region), track per-channel max
#pragma unroll
  for (int p = 0; p < 8; ++p)
    acc[p][0] = acc[p][1] = acc[p][2] = acc[p][3] = 0.f;
  mm_tile<DM, DM>(As, g2_w, Ws, tid, pbase, c4, acc);
  {
    float4 bb = *(const float4*)(g2_b + c4);
    float mx0 = -3.4e38f, mx1 = -3.4e38f, mx2 = -3.4e38f, mx3 = -3.4e38f;
#pragma unroll
    for (int p = 0; p < 8; ++p) {
      float4 L;
      L.x = acc[p][0] + bb.x; L.y = acc[p][1] + bb.y;
      L.z = acc[p][2] + bb.z; L.w = acc[p][3] + bb.w;
      *(float4*)(out_logits + (p0 + pbase + p) * DM + c4) = L;
      mx0 = fmaxf(mx0, L.x); mx1 = fmaxf(mx1, L.y);
      mx2 = fmaxf(mx2, L.z); mx3 = fmaxf(mx3, L.w);
    }
    __syncthreads();                      // g2 mm's Ws readers done
    Ws[tm * DM + c4 + 0] = mx0; Ws[tm * DM + c4 + 1] = mx1;
    Ws[tm * DM + c4 + 2] = mx2; Ws[tm * DM + c4 + 3] = mx3;
    __syncthreads();
    if (tid < DM) {
      float m = Ws[tid];
#pragma unroll
      for (int r = 1; r < 8; ++r) m = fmaxf(m, Ws[r * DM + tid]);
      atomicMax(&maxenc[b * DM + tid], fenc(m));
    }
  }

  // G = PE + X @ wv -> bf16 global
#pragma unroll
  for (int p = 0; p < 8; ++p) {
    acc[p][0] = pe[p][0]; acc[p][1] = pe[p][1];
    acc[p][2] = pe[p][2]; acc[p][3] = pe[p][3];
  }
  mm_tile<DM, DM>(Xs, wv_w, Ws, tid, pbase, c4, acc);
#pragma unroll
  for (int p = 0; p < 8; ++p) {
    ushort4 g;
    g.x = f2bf(acc[p][0]); g.y = f2bf(acc[p][1]);
    g.z = f2bf(acc[p][2]); g.w = f2bf(acc[p][3]);
    *(ushort4*)(Gbf + (p0 + pbase + p) * DM + c4) = g;
  }
}

// ---------- K2: per-channel sum of exp((l-m)*SCALE) ----------
__global__ __launch_bounds__(256) void k2_kernel(const float* __restrict__ logits,
                                                 const unsigned* __restrict__ maxenc,
                                                 float* __restrict__ sums) {
  __shared__ float red[8 * DM];
  const int tid = threadIdx.x;
  const int c4 = (tid & 31) * 4, r = tid >> 5;
  const long long pb = (long long)blockIdx.x * 256;
  const int b = (int)(pb >> 16);
  float4 m;
  m.x = fdec(maxenc[b * DM + c4 + 0]); m.y = fdec(maxenc[b * DM + c4 + 1]);
  m.z = fdec(maxenc[b * DM + c4 + 2]); m.w = fdec(maxenc[b * DM + c4 + 3]);
  float4 s = {0.f, 0.f, 0.f, 0.f};
  for (int i = 0; i < 32; ++i) {
    long long p = pb + r + (long long)i * 8;
    float4 l = *(const float4*)(logits + p * DM + c4);
    s.x += __expf((l.x - m.x) * SCALEF);
    s.y += __expf((l.y - m.y) * SCALEF);
    s.z += __expf((l.z - m.z) * SCALEF);
    s.w += __expf((l.w - m.w) * SCALEF);
  }
  *(float4*)(red + r * DM + c4) = s;
  __syncthreads();
  if (tid < DM) {
    float t = 0.f;
#pragma unroll
    for (int rr = 0; rr < 8; ++rr) t += red[rr * DM + tid];
    atomicAdd(&sums[b * DM + tid], t);
  }
}

// ---------- K3: normalize -> attn; res = (attn*G) @ fc2 + fc2_b + features ----------
__global__ __launch_bounds__(256) void k3_kernel(
    float* __restrict__ attn_io,                 // logits in, attn out (in place)
    float* __restrict__ out_res,
    const unsigned short* __restrict__ Gbf,
    const float* __restrict__ sums, const unsigned* __restrict__ maxenc,
    const float* __restrict__ fc2_w, const float* __restrict__ fc2_b,
    const float* __restrict__ features) {
  __shared__ float Ys[64 * DM];
  __shared__ float W2[DM * DP];
  const int tid = threadIdx.x;
#pragma unroll
  for (int j = 0; j < 8; ++j)
    ((float4*)W2)[tid + j * 256] = ((const float4*)fc2_w)[tid + j * 256];

  const long long p0 = (long long)blockIdx.x * 64;
  const int b = (int)(p0 >> 16);
  const int tn = tid & 31, tm = tid >> 5;
  const int c4 = tn * 4, pbase = tm * 8;

  float4 m, sv;
  m.x = fdec(maxenc[b * DM + c4 + 0]); m.y = fdec(maxenc[b * DM + c4 + 1]);
  m.z = fdec(maxenc[b * DM + c4 + 2]); m.w = fdec(maxenc[b * DM + c4 + 3]);
  sv.x = 1.f / sums[b * DM + c4 + 0]; sv.y = 1.f / sums[b * DM + c4 + 1];
  sv.z = 1.f / sums[b * DM + c4 + 2]; sv.w = 1.f / sums[b * DM + c4 + 3];

#pragma unroll
  for (int p = 0; p < 8; ++p) {
    long long idx = (p0 + pbase + p) * DM + c4;
    float4 l = *(const float4*)(attn_io + idx);
    float4 a;
    a.x = __expf((l.x - m.x) * SCALEF) * sv.x;
    a.y = __expf((l.y - m.y) * SCALEF) * sv.y;
    a.z = __expf((l.z - m.z) * SCALEF) * sv.z;
    a.w = __expf((l.w - m.w) * SCALEF) * sv.w;
    *(float4*)(attn_io + idx) = a;
    ushort4 g = *(const ushort4*)(Gbf + idx);
    float4 y;
    y.x = a.x * bf2f(g.x); y.y = a.y * bf2f(g.y);
    y.z = a.z * bf2f(g.z); y.w = a.w * bf2f(g.w);
    *(float4*)(Ys + (pbase + p) * DM + c4) = y;
  }
  __syncthreads();

  const int tn2 = tid & 15, tm2 = tid >> 4;
  const int c4b = tn2 * 4, pb2 = tm2 * 4;
  float acc[4][4];
#pragma unroll
  for (int p = 0; p < 4; ++p)
    acc[p][0] = acc[p][1] = acc[p][2] = acc[p][3] = 0.f;

  for (int k = 0; k < DM; k += 4) {
    float4 a4[4];
#pragma unroll
    for (int p = 0; p < 4; ++p)
      a4[p] = *(const float4*)(Ys + (pb2 + p) * DM + k);
#pragma unroll
    for (int i = 0; i < 4; ++i) {
      float4 w4 = *(const float4*)(W2 + (k + i) * DP + c4b);
#pragma unroll
      for (int p = 0; p < 4; ++p) {
        float a = (i == 0) ? a4[p].x : (i == 1) ? a4[p].y : (i == 2) ? a4[p].z : a4[p].w;
        acc[p][0] = fmaf(a, w4.x, acc[p][0]);
        acc[p][1] = fmaf(a, w4.y, acc[p][1]);
        acc[p][2] = fmaf(a, w4.z, acc[p][2]);
        acc[p][3] = fmaf(a, w4.w, acc[p][3]);
      }
    }
  }
  float4 bb = *(const float4*)(fc2_b + c4b);
#pragma unroll
  for (int p = 0; p < 4; ++p) {
    float4 ft = *(const float4*)(features + (p0 + pb2 + p) * DP + c4b);
    float4 o;
    o.x = acc[p][0] + bb.x + ft.x; o.y = acc[p][1] + bb.y + ft.y;
    o.z = acc[p][2] + bb.z + ft.z; o.w = acc[p][3] + bb.w + ft.w;
    *(float4*)(out_res + (p0 + pb2 + p) * DP + c4b) = o;
  }
}

extern "C" void kernel_launch(void* const* d_in, const int* in_sizes, int n_in,
                              void* d_out, int out_size, void* d_ws, size_t ws_size,
                              hipStream_t stream) {
  const float* xyz      = (const float*)d_in[0];
  const float* features = (const float*)d_in[1];
  const float* fc1_w    = (const float*)d_in[2];
  const float* fc1_b    = (const float*)d_in[3];
  const float* fc2_w    = (const float*)d_in[4];
  const float* fc2_b    = (const float*)d_in[5];
  const float* d1_w     = (const float*)d_in[6];
  const float* d1_b     = (const float*)d_in[7];
  const float* d2_w     = (const float*)d_in[8];
  const float* d2_b     = (const float*)d_in[9];
  const float* g1_w     = (const float*)d_in[10];
  const float* g1_b     = (const float*)d_in[11];
  const float* g2_w     = (const float*)d_in[12];
  const float* g2_b     = (const float*)d_in[13];
  const float* wq       = (const float*)d_in[14];
  const float* wk       = (const float*)d_in[15];
  const float* wv       = (const float*)d_in[16];

  float* out_res  = (float*)d_out;
  float* out_attn = out_res + (long long)BB * NN * DP;   // logits scratch, then attn

  float*    sums   = (float*)d_ws;                        // [256]
  unsigned* maxenc = (unsigned*)d_ws + 256;               // [256]
  float*    wqk    = (float*)d_ws + 512;                  // [16384]
  unsigned short* Gbf = (unsigned short*)((char*)d_ws + (512 + DM * DM) * sizeof(float));

  hipLaunchKernelGGL(k0_kernel, dim3(64), dim3(256), 0, stream, wq, wk, wqk, (float*)d_ws);
  hipLaunchKernelGGL(k1_kernel, dim3((BB * NN) / 64), dim3(256), 0, stream,
                     xyz, features, fc1_w, fc1_b, d1_w, d1_b, d2_w, d2_b,
                     g1_w, g1_b, g2_w, g2_b, wqk, wv, out_attn, Gbf, maxenc);
  hipLaunchKernelGGL(k2_kernel, dim3((BB * NN) / 256), dim3(256), 0, stream,
                     out_attn, maxenc, sums);
  hipLaunchKernelGGL(k3_kernel, dim3((BB * NN) / 64), dim3(256), 0, stream,
                     out_attn, out_res, Gbf, sums, maxenc, fc2_w, fc2_b, features);
}

// Round 2
// 281.162 us; speedup vs baseline: 2.3270x; 2.3270x over previous
//
#include <hip/hip_runtime.h>
#include <hip/hip_bf16.h>

#define BB 2
#define NN 65536
#define DP 64
#define DM 128
#define SCALEF 0.08838834764831845f   // 1/sqrt(128)

typedef __attribute__((ext_vector_type(8))) short short8v;
typedef __attribute__((ext_vector_type(4))) float float4v;

// ---------- helpers ----------
__device__ __forceinline__ unsigned fenc(float f) {
  unsigned u = __float_as_uint(f);
  return (u & 0x80000000u) ? ~u : (u | 0x80000000u);   // order-preserving float->uint
}
__device__ __forceinline__ float fdec(unsigned u) {
  unsigned v = (u & 0x80000000u) ? (u & 0x7FFFFFFFu) : ~u;
  return __uint_as_float(v);
}
__device__ __forceinline__ unsigned short f2bf(float f) {   // RNE f32->bf16
  unsigned u = __float_as_uint(f);
  u += 0x7FFFu + ((u >> 16) & 1u);
  return (unsigned short)(u >> 16);
}
__device__ __forceinline__ float bf2f(unsigned short h) {
  return __uint_as_float(((unsigned)h) << 16);
}

// ---------- K0: transpose+convert weights to bf16 [n][k]; wqk = wq-wk; zero accum ----------
__global__ __launch_bounds__(256) void k0_kernel(
    const float* __restrict__ wq, const float* __restrict__ wk,
    const float* __restrict__ fc1_w, const float* __restrict__ d2_w,
    const float* __restrict__ g1_w, const float* __restrict__ g2_w,
    const float* __restrict__ wv_w,
    float* __restrict__ zbuf,
    short* __restrict__ d2t, short* __restrict__ fc1t, short* __restrict__ wqkt,
    short* __restrict__ g1t, short* __restrict__ g2t, short* __restrict__ wvt) {
  int t = threadIdx.x, bi = blockIdx.x;
  if (bi < 2) zbuf[bi * 256 + t] = 0.f;       // sums[256] + maxenc[256]
  int mat = bi >> 5, blk = bi & 31;
  if (mat == 1) {                              // fc1: [64][128] -> [128][64]
    int i = blk * 256 + t;
    int n = i >> 6, k = i & 63;
    fc1t[n * 64 + k] = (short)f2bf(fc1_w[k * 128 + n]);
  } else {
    const float* src = (mat == 0) ? d2_w : (mat == 2) ? wq : (mat == 3) ? g1_w
                     : (mat == 4) ? g2_w : wv_w;
    short* dst = (mat == 0) ? d2t : (mat == 2) ? wqkt : (mat == 3) ? g1t
               : (mat == 4) ? g2t : wvt;
#pragma unroll
    for (int j = 0; j < 2; ++j) {
      int i = blk * 512 + t + j * 256;
      int n = i >> 7, k = i & 127;
      float v = src[k * 128 + n];
      if (mat == 2) v -= wk[k * 128 + n];
      dst[n * 128 + k] = (short)f2bf(v);
    }
  }
}

// ---------- MFMA GEMM core ----------
// acc[4][2] over output tile 64(m) x 32(n-strip per wave). A in LDS [64][136] bf16,
// Wt global bf16 [128][K], staged in 64-wide K halves into Ws [128][72].
template<int K>
__device__ __forceinline__ void gemm_mfma(const short* __restrict__ A,
                                          const short* __restrict__ Wt,
                                          short* __restrict__ Ws,
                                          int tid, int wv, int col, int quad,
                                          float4v acc[4][2]) {
#pragma unroll
  for (int h = 0; h < K / 64; ++h) {
    __syncthreads();                       // prior Ws readers / A writers done
#pragma unroll
    for (int j = 0; j < 4; ++j) {          // stage 128x64 bf16 chunk (16 KB)
      int i = tid + j * 256;
      int row = i >> 3, kc = (i & 7) * 8;
      *(short8v*)(Ws + row * 72 + kc) = *(const short8v*)(Wt + row * K + h * 64 + kc);
    }
    __syncthreads();
#pragma unroll
    for (int ks = 0; ks < 2; ++ks) {
      int ko = h * 64 + ks * 32 + quad * 8;
      int wo = ks * 32 + quad * 8;
      short8v b0 = *(const short8v*)(Ws + (wv * 32 + col) * 72 + wo);
      short8v b1 = *(const short8v*)(Ws + (wv * 32 + 16 + col) * 72 + wo);
#pragma unroll
      for (int mt = 0; mt < 4; ++mt) {
        short8v a = *(const short8v*)(A + (mt * 16 + col) * 136 + ko);
        acc[mt][0] = __builtin_amdgcn_mfma_f32_16x16x32_bf16(a, b0, acc[mt][0], 0, 0, 0);
        acc[mt][1] = __builtin_amdgcn_mfma_f32_16x16x32_bf16(a, b1, acc[mt][1], 0, 0, 0);
      }
    }
  }
}

// write acc (+bias, optional relu) as bf16 into LDS activation buffer [64][136]
__device__ __forceinline__ void store_tile(short* __restrict__ dst,
                                           const float4v acc[4][2],
                                           int wv, int col, int quad,
                                           float b0, float b1, bool do_relu) {
#pragma unroll
  for (int mt = 0; mt < 4; ++mt)
#pragma unroll
    for (int nt = 0; nt < 2; ++nt) {
      float bias = nt ? b1 : b0;
#pragma unroll
      for (int r = 0; r < 4; ++r) {
        float v = acc[mt][nt][r] + bias;
        if (do_relu) v = fmaxf(v, 0.f);
        dst[(mt * 16 + quad * 4 + r) * 136 + wv * 32 + nt * 16 + col] = (short)f2bf(v);
      }
    }
}

// ---------- K1: full chain to logits + G, MFMA ----------
__global__ __launch_bounds__(256, 2) void k1_kernel(
    const float* __restrict__ xyz, const float* __restrict__ features,
    const short* __restrict__ fc1t, const float* __restrict__ fc1_b,
    const float* __restrict__ d1_w, const float* __restrict__ d1_b,
    const short* __restrict__ d2t, const float* __restrict__ d2_b,
    const short* __restrict__ g1t, const float* __restrict__ g1_b,
    const short* __restrict__ g2t, const float* __restrict__ g2_b,
    const short* __restrict__ wqkt, const short* __restrict__ wvt,
    float* __restrict__ out_logits, unsigned short* __restrict__ Gbf,
    unsigned* __restrict__ maxenc) {
  __shared__ short As[64 * 136];   // R -> F -> T -> H (bf16, rows padded)
  __shared__ short Xs[64 * 136];   // X (persists); float scratch for xyz early
  __shared__ short Ws[128 * 72];   // weight K-half staging

  const int tid = threadIdx.x;
  const int wv = tid >> 6;
  const int lane = tid & 63;
  const int col = lane & 15, quad = lane >> 4;
  const long long p0 = (long long)blockIdx.x * 64;
  const int b = (int)(p0 >> 16);

  // xyz tile -> Xs-as-float scratch
  float* xf = (float*)Xs;
  if (tid < 192) xf[tid] = xyz[p0 * 3 + tid];
  __syncthreads();

  // R = relu(xyz @ d1 + d1_b) -> As (bf16)
  {
    const int tn = tid & 31, tm = tid >> 5;
    const int c4 = tn * 4, pbase = tm * 8;
    float4 w0 = *(const float4*)(d1_w + c4);
    float4 w1 = *(const float4*)(d1_w + 128 + c4);
    float4 w2 = *(const float4*)(d1_w + 256 + c4);
    float4 bb = *(const float4*)(d1_b + c4);
#pragma unroll
    for (int p = 0; p < 8; ++p) {
      float x0 = xf[(pbase + p) * 3 + 0];
      float x1 = xf[(pbase + p) * 3 + 1];
      float x2 = xf[(pbase + p) * 3 + 2];
      short4 rr;
      rr.x = (short)f2bf(fmaxf(0.f, fmaf(x0, w0.x, fmaf(x1, w1.x, fmaf(x2, w2.x, bb.x)))));
      rr.y = (short)f2bf(fmaxf(0.f, fmaf(x0, w0.y, fmaf(x1, w1.y, fmaf(x2, w2.y, bb.y)))));
      rr.z = (short)f2bf(fmaxf(0.f, fmaf(x0, w0.z, fmaf(x1, w1.z, fmaf(x2, w2.z, bb.z)))));
      rr.w = (short)f2bf(fmaxf(0.f, fmaf(x0, w0.w, fmaf(x1, w1.w, fmaf(x2, w2.w, bb.w)))));
      *(short4*)(As + (pbase + p) * 136 + c4) = rr;
    }
  }

  const int ch0 = wv * 32 + col, ch1 = ch0 + 16;
  float4v pe[4][2], acc[4][2];

  // PE = R @ d2 + d2_b (regs)
#pragma unroll
  for (int mt = 0; mt < 4; ++mt)
#pragma unroll
    for (int nt = 0; nt < 2; ++nt)
#pragma unroll
      for (int r = 0; r < 4; ++r) acc[mt][nt][r] = 0.f;
  gemm_mfma<128>(As, d2t, Ws, tid, wv, col, quad, acc);
  {
    float b0 = d2_b[ch0], b1 = d2_b[ch1];
#pragma unroll
    for (int mt = 0; mt < 4; ++mt)
#pragma unroll
      for (int r = 0; r < 4; ++r) {
        pe[mt][0][r] = acc[mt][0][r] + b0;
        pe[mt][1][r] = acc[mt][1][r] + b1;
      }
  }
  __syncthreads();   // all As(R) readers done before overwriting with F

  // F -> As (bf16), 64x64
#pragma unroll
  for (int j = 0; j < 4; ++j) {
    int c = tid + j * 256;
    float4 f = *(const float4*)(features + p0 * 64 + (long long)c * 4);
    int row = c >> 4, cp = (c & 15) * 4;
    short4 s;
    s.x = (short)f2bf(f.x); s.y = (short)f2bf(f.y);
    s.z = (short)f2bf(f.z); s.w = (short)f2bf(f.w);
    *(short4*)(As + row * 136 + cp) = s;
  }
  // X = F @ fc1 + fc1_b -> Xs (gemm's first barrier covers the F writes)
#pragma unroll
  for (int mt = 0; mt < 4; ++mt)
#pragma unroll
    for (int nt = 0; nt < 2; ++nt)
#pragma unroll
      for (int r = 0; r < 4; ++r) acc[mt][nt][r] = 0.f;
  gemm_mfma<64>(As, fc1t, Ws, tid, wv, col, quad, acc);
  store_tile(Xs, acc, wv, col, quad, fc1_b[ch0], fc1_b[ch1], false);

  // T = PE + X @ wqk -> As (first barrier covers Xs writes; As not read inside)
#pragma unroll
  for (int mt = 0; mt < 4; ++mt)
#pragma unroll
    for (int nt = 0; nt < 2; ++nt)
#pragma unroll
      for (int r = 0; r < 4; ++r) acc[mt][nt][r] = pe[mt][nt][r];
  gemm_mfma<128>(Xs, wqkt, Ws, tid, wv, col, quad, acc);
  store_tile(As, acc, wv, col, quad, 0.f, 0.f, false);

  // H = relu(T @ g1 + g1_b) -> As (in place; barrier before overwrite)
#pragma unroll
  for (int mt = 0; mt < 4; ++mt)
#pragma unroll
    for (int nt = 0; nt < 2; ++nt)
#pragma unroll
      for (int r = 0; r < 4; ++r) acc[mt][nt][r] = 0.f;
  gemm_mfma<128>(As, g1t, Ws, tid, wv, col, quad, acc);
  __syncthreads();
  store_tile(As, acc, wv, col, quad, g1_b[ch0], g1_b[ch1], true);

  // L = H @ g2 + g2_b -> global logits; per-channel max via shfl + atomic
#pragma unroll
  for (int mt = 0; mt < 4; ++mt)
#pragma unroll
    for (int nt = 0; nt < 2; ++nt)
#pragma unroll
      for (int r = 0; r < 4; ++r) acc[mt][nt][r] = 0.f;
  gemm_mfma<128>(As, g2t, Ws, tid, wv, col, quad, acc);
  {
    float b0 = g2_b[ch0], b1 = g2_b[ch1];
    float mx0 = -3.4e38f, mx1 = -3.4e38f;
#pragma unroll
    for (int mt = 0; mt < 4; ++mt)
#pragma unroll
      for (int r = 0; r < 4; ++r) {
        long long row = p0 + mt * 16 + quad * 4 + r;
        float v0 = acc[mt][0][r] + b0;
        float v1 = acc[mt][1][r] + b1;
        out_logits[row * DM + ch0] = v0;
        out_logits[row * DM + ch1] = v1;
        mx0 = fmaxf(mx0, v0); mx1 = fmaxf(mx1, v1);
      }
    mx0 = fmaxf(mx0, __shfl_xor(mx0, 16, 64));
    mx0 = fmaxf(mx0, __shfl_xor(mx0, 32, 64));
    mx1 = fmaxf(mx1, __shfl_xor(mx1, 16, 64));
    mx1 = fmaxf(mx1, __shfl_xor(mx1, 32, 64));
    if (quad == 0) {
      atomicMax(&maxenc[b * DM + ch0], fenc(mx0));
      atomicMax(&maxenc[b * DM + ch1], fenc(mx1));
    }
  }

  // G = PE + X @ wv -> bf16 global (first barrier covers g2's Ws readers)
#pragma unroll
  for (int mt = 0; mt < 4; ++mt)
#pragma unroll
    for (int nt = 0; nt < 2; ++nt)
#pragma unroll
      for (int r = 0; r < 4; ++r) acc[mt][nt][r] = pe[mt][nt][r];
  gemm_mfma<128>(Xs, wvt, Ws, tid, wv, col, quad, acc);
#pragma unroll
  for (int mt = 0; mt < 4; ++mt)
#pragma unroll
    for (int r = 0; r < 4; ++r) {
      long long row = p0 + mt * 16 + quad * 4 + r;
      Gbf[row * DM + ch0] = f2bf(acc[mt][0][r]);
      Gbf[row * DM + ch1] = f2bf(acc[mt][1][r]);
    }
}

// ---------- K2: per-channel sum of exp((l-m)*SCALE) ----------
__global__ __launch_bounds__(256) void k2_kernel(const float* __restrict__ logits,
                                                 const unsigned* __restrict__ maxenc,
                                                 float* __restrict__ sums) {
  __shared__ float red[8 * DM];
  const int tid = threadIdx.x;
  const int c4 = (tid & 31) * 4, r = tid >> 5;
  const long long pb = (long long)blockIdx.x * 256;
  const int b = (int)(pb >> 16);
  float4 m;
  m.x = fdec(maxenc[b * DM + c4 + 0]); m.y = fdec(maxenc[b * DM + c4 + 1]);
  m.z = fdec(maxenc[b * DM + c4 + 2]); m.w = fdec(maxenc[b * DM + c4 + 3]);
  float4 s = {0.f, 0.f, 0.f, 0.f};
  for (int i = 0; i < 32; ++i) {
    long long p = pb + r + (long long)i * 8;
    float4 l = *(const float4*)(logits + p * DM + c4);
    s.x += __expf((l.x - m.x) * SCALEF);
    s.y += __expf((l.y - m.y) * SCALEF);
    s.z += __expf((l.z - m.z) * SCALEF);
    s.w += __expf((l.w - m.w) * SCALEF);
  }
  *(float4*)(red + r * DM + c4) = s;
  __syncthreads();
  if (tid < DM) {
    float t = 0.f;
#pragma unroll
    for (int rr = 0; rr < 8; ++rr) t += red[rr * DM + tid];
    atomicAdd(&sums[b * DM + tid], t);
  }
}

// ---------- K3: normalize -> attn; res = (attn*G) @ fc2 + fc2_b + features ----------
// NOTE: Gbf aliases the res output region byte-exactly per point; each block reads
// its own 64-point G range into LDS, barriers, then overwrites the same range.
__global__ __launch_bounds__(256) void k3_kernel(
    float* __restrict__ attn_io,
    float* __restrict__ out_res,
    const unsigned short* __restrict__ Gbf,
    const float* __restrict__ sums, const unsigned* __restrict__ maxenc,
    const float* __restrict__ fc2_w, const float* __restrict__ fc2_b,
    const float* __restrict__ features) {
  __shared__ float Ys[64 * DM];
  __shared__ float W2[DM * DP];
  const int tid = threadIdx.x;
#pragma unroll
  for (int j = 0; j < 8; ++j)
    ((float4*)W2)[tid + j * 256] = ((const float4*)fc2_w)[tid + j * 256];

  const long long p0 = (long long)blockIdx.x * 64;
  const int b = (int)(p0 >> 16);
  const int tn = tid & 31, tm = tid >> 5;
  const int c4 = tn * 4, pbase = tm * 8;

  float4 m, sv;
  m.x = fdec(maxenc[b * DM + c4 + 0]); m.y = fdec(maxenc[b * DM + c4 + 1]);
  m.z = fdec(maxenc[b * DM + c4 + 2]); m.w = fdec(maxenc[b * DM + c4 + 3]);
  sv.x = 1.f / sums[b * DM + c4 + 0]; sv.y = 1.f / sums[b * DM + c4 + 1];
  sv.z = 1.f / sums[b * DM + c4 + 2]; sv.w = 1.f / sums[b * DM + c4 + 3];

#pragma unroll
  for (int p = 0; p < 8; ++p) {
    long long idx = (p0 + pbase + p) * DM + c4;
    float4 l = *(const float4*)(attn_io + idx);
    float4 a;
    a.x = __expf((l.x - m.x) * SCALEF) * sv.x;
    a.y = __expf((l.y - m.y) * SCALEF) * sv.y;
    a.z = __expf((l.z - m.z) * SCALEF) * sv.z;
    a.w = __expf((l.w - m.w) * SCALEF) * sv.w;
    *(float4*)(attn_io + idx) = a;
    ushort4 g = *(const ushort4*)(Gbf + idx);
    float4 y;
    y.x = a.x * bf2f(g.x); y.y = a.y * bf2f(g.y);
    y.z = a.z * bf2f(g.z); y.w = a.w * bf2f(g.w);
    *(float4*)(Ys + (pbase + p) * DM + c4) = y;
  }
  __syncthreads();

  const int tn2 = tid & 15, tm2 = tid >> 4;
  const int c4b = tn2 * 4, pb2 = tm2 * 4;
  float acc[4][4];
#pragma unroll
  for (int p = 0; p < 4; ++p)
    acc[p][0] = acc[p][1] = acc[p][2] = acc[p][3] = 0.f;

  for (int k = 0; k < DM; k += 4) {
    float4 a4[4];
#pragma unroll
    for (int p = 0; p < 4; ++p)
      a4[p] = *(const float4*)(Ys + (pb2 + p) * DM + k);
#pragma unroll
    for (int i = 0; i < 4; ++i) {
      float4 w4 = *(const float4*)(W2 + (k + i) * DP + c4b);
#pragma unroll
      for (int p = 0; p < 4; ++p) {
        float a = (i == 0) ? a4[p].x : (i == 1) ? a4[p].y : (i == 2) ? a4[p].z : a4[p].w;
        acc[p][0] = fmaf(a, w4.x, acc[p][0]);
        acc[p][1] = fmaf(a, w4.y, acc[p][1]);
        acc[p][2] = fmaf(a, w4.z, acc[p][2]);
        acc[p][3] = fmaf(a, w4.w, acc[p][3]);
      }
    }
  }
  float4 bb = *(const float4*)(fc2_b + c4b);
#pragma unroll
  for (int p = 0; p < 4; ++p) {
    float4 ft = *(const float4*)(features + (p0 + pb2 + p) * DP + c4b);
    float4 o;
    o.x = acc[p][0] + bb.x + ft.x; o.y = acc[p][1] + bb.y + ft.y;
    o.z = acc[p][2] + bb.z + ft.z; o.w = acc[p][3] + bb.w + ft.w;
    *(float4*)(out_res + (p0 + pb2 + p) * DP + c4b) = o;
  }
}

extern "C" void kernel_launch(void* const* d_in, const int* in_sizes, int n_in,
                              void* d_out, int out_size, void* d_ws, size_t ws_size,
                              hipStream_t stream) {
  const float* xyz      = (const float*)d_in[0];
  const float* features = (const float*)d_in[1];
  const float* fc1_w    = (const float*)d_in[2];
  const float* fc1_b    = (const float*)d_in[3];
  const float* fc2_w    = (const float*)d_in[4];
  const float* fc2_b    = (const float*)d_in[5];
  const float* d1_w     = (const float*)d_in[6];
  const float* d1_b     = (const float*)d_in[7];
  const float* d2_w     = (const float*)d_in[8];
  const float* d2_b     = (const float*)d_in[9];
  const float* g1_w     = (const float*)d_in[10];
  const float* g1_b     = (const float*)d_in[11];
  const float* g2_w     = (const float*)d_in[12];
  const float* g2_b     = (const float*)d_in[13];
  const float* wq       = (const float*)d_in[14];
  const float* wk       = (const float*)d_in[15];
  const float* wv       = (const float*)d_in[16];

  float* out_res  = (float*)d_out;
  float* out_attn = out_res + (long long)BB * NN * DP;   // logits scratch, then attn

  float*    sums   = (float*)d_ws;                        // [256]
  unsigned* maxenc = (unsigned*)d_ws + 256;               // [256]
  short* wbase = (short*)((float*)d_ws + 512);
  short* d2t  = wbase;                 // 128*128
  short* fc1t = d2t + 16384;           // 128*64
  short* wqkt = fc1t + 8192;           // 128*128
  short* g1t  = wqkt + 16384;
  short* g2t  = g1t + 16384;
  short* wvt  = g2t + 16384;
  unsigned short* Gbf = (unsigned short*)d_out;   // aliases res region (byte-exact per point)

  hipLaunchKernelGGL(k0_kernel, dim3(192), dim3(256), 0, stream,
                     wq, wk, fc1_w, d2_w, g1_w, g2_w, wv,
                     (float*)d_ws, d2t, fc1t, wqkt, g1t, g2t, wvt);
  hipLaunchKernelGGL(k1_kernel, dim3((BB * NN) / 64), dim3(256), 0, stream,
                     xyz, features, fc1t, fc1_b, d1_w, d1_b, d2t, d2_b,
                     g1t, g1_b, g2t, g2_b, wqkt, wvt, out_attn, Gbf, maxenc);
  hipLaunchKernelGGL(k2_kernel, dim3((BB * NN) / 256), dim3(256), 0, stream,
                     out_attn, maxenc, sums);
  hipLaunchKernelGGL(k3_kernel, dim3((BB * NN) / 64), dim3(256), 0, stream,
                     out_attn, out_res, Gbf, sums, maxenc, fc2_w, fc2_b, features);
}

// Round 3
// 237.109 us; speedup vs baseline: 2.7594x; 1.1858x over previous
//
#include <hip/hip_runtime.h>
#include <hip/hip_bf16.h>

#define BB 2
#define NN 65536
#define DP 64
#define DM 128
#define SCALEF 0.08838834764831845f   // 1/sqrt(128)

typedef __attribute__((ext_vector_type(8))) short short8v;
typedef __attribute__((ext_vector_type(4))) float float4v;

// ---------- helpers ----------
__device__ __forceinline__ unsigned short f2bf(float f) {   // RNE f32->bf16
  unsigned u = __float_as_uint(f);
  u += 0x7FFFu + ((u >> 16) & 1u);
  return (unsigned short)(u >> 16);
}
__device__ __forceinline__ float bf2f(unsigned short h) {
  return __uint_as_float(((unsigned)h) << 16);
}

// ---------- K0: transpose+convert weights to bf16 [n][k]; wqk = wq-wk; zero sums ----------
__global__ __launch_bounds__(256) void k0_kernel(
    const float* __restrict__ wq, const float* __restrict__ wk,
    const float* __restrict__ fc1_w, const float* __restrict__ fc2_w,
    const float* __restrict__ d2_w, const float* __restrict__ g1_w,
    const float* __restrict__ g2_w, const float* __restrict__ wv_w,
    float* __restrict__ sums,
    short* __restrict__ d2t, short* __restrict__ fc1t, short* __restrict__ wqkt,
    short* __restrict__ g1t, short* __restrict__ g2t, short* __restrict__ wvt,
    short* __restrict__ fc2t) {
  int t = threadIdx.x, bi = blockIdx.x;
  if (bi == 0) sums[t] = 0.f;                  // sums[BB*DM]
  int mat = bi >> 5, blk = bi & 31;
  if (mat == 1) {                              // fc1: [64][128] -> fc1t[128][64]
    int i = blk * 256 + t;
    int n = i >> 6, k = i & 63;
    fc1t[n * 64 + k] = (short)f2bf(fc1_w[k * 128 + n]);
  } else if (mat == 6) {                       // fc2: [128][64] -> fc2t[64][128]
    int i = blk * 256 + t;
    int n = i >> 7, k = i & 127;
    fc2t[n * 128 + k] = (short)f2bf(fc2_w[k * 64 + n]);
  } else {
    const float* src = (mat == 0) ? d2_w : (mat == 2) ? wq : (mat == 3) ? g1_w
                     : (mat == 4) ? g2_w : wv_w;
    short* dst = (mat == 0) ? d2t : (mat == 2) ? wqkt : (mat == 3) ? g1t
               : (mat == 4) ? g2t : wvt;
#pragma unroll
    for (int j = 0; j < 2; ++j) {
      int i = blk * 512 + t + j * 256;
      int n = i >> 7, k = i & 127;
      float v = src[k * 128 + n];
      if (mat == 2) v -= wk[k * 128 + n];
      dst[n * 128 + k] = (short)f2bf(v);
    }
  }
}

// ---------- register-resident B fragments (weights L2-hot, no LDS staging) ----------
template<int K>
__device__ __forceinline__ void loadB(const short* __restrict__ Wt,
                                      int wid, int col, int quad, short8v b[2][4]) {
#pragma unroll
  for (int nt = 0; nt < 2; ++nt)
#pragma unroll
    for (int kt = 0; kt < K / 32; ++kt)
      b[nt][kt] = *(const short8v*)(Wt + (wid * 32 + nt * 16 + col) * K + kt * 32 + quad * 8);
}

template<int K>
__device__ __forceinline__ void gemm_compute(const short* __restrict__ A,
                                             const short8v b[2][4],
                                             int col, int quad, float4v acc[4][2]) {
#pragma unroll
  for (int kt = 0; kt < K / 32; ++kt) {
#pragma unroll
    for (int mt = 0; mt < 4; ++mt) {
      short8v a = *(const short8v*)(A + (mt * 16 + col) * 136 + kt * 32 + quad * 8);
      acc[mt][0] = __builtin_amdgcn_mfma_f32_16x16x32_bf16(a, b[0][kt], acc[mt][0], 0, 0, 0);
      acc[mt][1] = __builtin_amdgcn_mfma_f32_16x16x32_bf16(a, b[1][kt], acc[mt][1], 0, 0, 0);
    }
  }
}

// write acc (+bias, optional relu) as bf16 into LDS activation buffer [64][136]
__device__ __forceinline__ void store_tile(short* __restrict__ dst,
                                           const float4v acc[4][2],
                                           int wid, int col, int quad,
                                           float b0, float b1, bool do_relu) {
#pragma unroll
  for (int mt = 0; mt < 4; ++mt)
#pragma unroll
    for (int nt = 0; nt < 2; ++nt) {
      float bias = nt ? b1 : b0;
#pragma unroll
      for (int r = 0; r < 4; ++r) {
        float v = acc[mt][nt][r] + bias;
        if (do_relu) v = fmaxf(v, 0.f);
        dst[(mt * 16 + quad * 4 + r) * 136 + wid * 32 + nt * 16 + col] = (short)f2bf(v);
      }
    }
}

#define ZERO_ACC(acc) \
  _Pragma("unroll") for (int mt = 0; mt < 4; ++mt) \
  _Pragma("unroll") for (int nt = 0; nt < 2; ++nt) \
  _Pragma("unroll") for (int r = 0; r < 4; ++r) acc[mt][nt][r] = 0.f;

// ---------- K1: full chain; writes E=exp(l*SCALE) bf16 + G bf16 + partial sums ----------
__global__ __launch_bounds__(256, 3) void k1_kernel(
    const float* __restrict__ xyz, const float* __restrict__ features,
    const short* __restrict__ fc1t, const float* __restrict__ fc1_b,
    const float* __restrict__ d1_w, const float* __restrict__ d1_b,
    const short* __restrict__ d2t, const float* __restrict__ d2_b,
    const short* __restrict__ g1t, const float* __restrict__ g1_b,
    const short* __restrict__ g2t, const float* __restrict__ g2_b,
    const short* __restrict__ wqkt, const short* __restrict__ wvt,
    unsigned short* __restrict__ Ebf, unsigned short* __restrict__ Gbf,
    float* __restrict__ sums) {
  __shared__ __align__(16) short As[64 * 136];   // R -> F -> T -> H
  __shared__ __align__(16) short Xs[64 * 136];   // xyz scratch, then X (persists)

  const int tid = threadIdx.x;
  const int wid = tid >> 6, lane = tid & 63;
  const int col = lane & 15, quad = lane >> 4;
  const long long p0 = (long long)blockIdx.x * 64;
  const int bi = (int)(p0 >> 16);

  short8v b[2][4];
  loadB<128>(d2t, wid, col, quad, b);            // prefetch d2 B over xyz/R phase

  float* xf = (float*)Xs;
  if (tid < 192) xf[tid] = xyz[p0 * 3 + tid];
  __syncthreads();                               // (1) xyz visible

  // R = relu(xyz @ d1 + d1_b) -> As (bf16)
  {
    const int tn = tid & 31, tm = tid >> 5;
    const int c4 = tn * 4, pbase = tm * 8;
    float4 w0 = *(const float4*)(d1_w + c4);
    float4 w1 = *(const float4*)(d1_w + 128 + c4);
    float4 w2 = *(const float4*)(d1_w + 256 + c4);
    float4 bb = *(const float4*)(d1_b + c4);
#pragma unroll
    for (int p = 0; p < 8; ++p) {
      float x0 = xf[(pbase + p) * 3 + 0];
      float x1 = xf[(pbase + p) * 3 + 1];
      float x2 = xf[(pbase + p) * 3 + 2];
      short4 rr;
      rr.x = (short)f2bf(fmaxf(0.f, fmaf(x0, w0.x, fmaf(x1, w1.x, fmaf(x2, w2.x, bb.x)))));
      rr.y = (short)f2bf(fmaxf(0.f, fmaf(x0, w0.y, fmaf(x1, w1.y, fmaf(x2, w2.y, bb.y)))));
      rr.z = (short)f2bf(fmaxf(0.f, fmaf(x0, w0.z, fmaf(x1, w1.z, fmaf(x2, w2.z, bb.z)))));
      rr.w = (short)f2bf(fmaxf(0.f, fmaf(x0, w0.w, fmaf(x1, w1.w, fmaf(x2, w2.w, bb.w)))));
      *(short4*)(As + (pbase + p) * 136 + c4) = rr;
    }
  }
  __syncthreads();                               // (2) R written

  const int ch0 = wid * 32 + col, ch1 = ch0 + 16;
  float4v pe[4][2], acc[4][2];

  // PE = R @ d2 + d2_b (regs)
  ZERO_ACC(acc)
  gemm_compute<128>(As, b, col, quad, acc);
  {
    float b0 = d2_b[ch0], b1 = d2_b[ch1];
#pragma unroll
    for (int mt = 0; mt < 4; ++mt)
#pragma unroll
      for (int r = 0; r < 4; ++r) {
        pe[mt][0][r] = acc[mt][0][r] + b0;
        pe[mt][1][r] = acc[mt][1][r] + b1;
      }
  }
  loadB<64>(fc1t, wid, col, quad, b);
  __syncthreads();                               // (3) d2's As readers done

  // F -> As (bf16), 64x64
#pragma unroll
  for (int j = 0; j < 4; ++j) {
    int c = tid + j * 256;
    float4 f = *(const float4*)(features + p0 * 64 + (long long)c * 4);
    int row = c >> 4, cp = (c & 15) * 4;
    short4 s;
    s.x = (short)f2bf(f.x); s.y = (short)f2bf(f.y);
    s.z = (short)f2bf(f.z); s.w = (short)f2bf(f.w);
    *(short4*)(As + row * 136 + cp) = s;
  }
  __syncthreads();                               // (4) F written

  // X = F @ fc1 + fc1_b -> Xs
  ZERO_ACC(acc)
  gemm_compute<64>(As, b, col, quad, acc);
  store_tile(Xs, acc, wid, col, quad, fc1_b[ch0], fc1_b[ch1], false);
  loadB<128>(wqkt, wid, col, quad, b);
  __syncthreads();                               // (5) Xs written; fc1's As reads done

  // T = PE + X @ wqk -> As
#pragma unroll
  for (int mt = 0; mt < 4; ++mt)
#pragma unroll
    for (int nt = 0; nt < 2; ++nt)
#pragma unroll
      for (int r = 0; r < 4; ++r) acc[mt][nt][r] = pe[mt][nt][r];
  gemm_compute<128>(Xs, b, col, quad, acc);
  store_tile(As, acc, wid, col, quad, 0.f, 0.f, false);
  loadB<128>(g1t, wid, col, quad, b);
  __syncthreads();                               // (6) T written

  // H = relu(T @ g1 + g1_b) -> As (in place)
  ZERO_ACC(acc)
  gemm_compute<128>(As, b, col, quad, acc);
  __syncthreads();                               // (7) T readers done
  store_tile(As, acc, wid, col, quad, g1_b[ch0], g1_b[ch1], true);
  loadB<128>(g2t, wid, col, quad, b);
  __syncthreads();                               // (8) H written

  // L = H @ g2 + g2_b; E = exp(L*SCALE) -> global bf16; per-channel partial sums
  ZERO_ACC(acc)
  gemm_compute<128>(As, b, col, quad, acc);
  {
    float b0 = g2_b[ch0], b1 = g2_b[ch1];
    float s0 = 0.f, s1 = 0.f;
#pragma unroll
    for (int mt = 0; mt < 4; ++mt)
#pragma unroll
      for (int r = 0; r < 4; ++r) {
        long long row = p0 + mt * 16 + quad * 4 + r;
        float e0 = __expf((acc[mt][0][r] + b0) * SCALEF);
        float e1 = __expf((acc[mt][1][r] + b1) * SCALEF);
        Ebf[row * DM + ch0] = f2bf(e0);
        Ebf[row * DM + ch1] = f2bf(e1);
        s0 += e0; s1 += e1;
      }
    s0 += __shfl_xor(s0, 16, 64); s0 += __shfl_xor(s0, 32, 64);
    s1 += __shfl_xor(s1, 16, 64); s1 += __shfl_xor(s1, 32, 64);
    if (quad == 0) {
      atomicAdd(&sums[bi * DM + ch0], s0);
      atomicAdd(&sums[bi * DM + ch1], s1);
    }
  }

  // G = PE + X @ wv -> global bf16 (Xs unchanged since X: no barrier needed)
  loadB<128>(wvt, wid, col, quad, b);
#pragma unroll
  for (int mt = 0; mt < 4; ++mt)
#pragma unroll
    for (int nt = 0; nt < 2; ++nt)
#pragma unroll
      for (int r = 0; r < 4; ++r) acc[mt][nt][r] = pe[mt][nt][r];
  gemm_compute<128>(Xs, b, col, quad, acc);
#pragma unroll
  for (int mt = 0; mt < 4; ++mt)
#pragma unroll
    for (int r = 0; r < 4; ++r) {
      long long row = p0 + mt * 16 + quad * 4 + r;
      Gbf[row * DM + ch0] = f2bf(acc[mt][0][r]);
      Gbf[row * DM + ch1] = f2bf(acc[mt][1][r]);
    }
}

// ---------- K3: attn = E/sum; res = bf16(attn*G) @ fc2 + fc2_b + features ----------
// Gbf aliases the res output region byte-exactly per point-row; each block reads its
// own 64 rows before the barrier and overwrites them after it.
__global__ __launch_bounds__(256) void k3_kernel(
    const unsigned short* __restrict__ Ebf, float* __restrict__ out_attn,
    float* __restrict__ out_res, const unsigned short* __restrict__ Gbf,
    const float* __restrict__ sums,
    const short* __restrict__ fc2t, const float* __restrict__ fc2_b,
    const float* __restrict__ features) {
  __shared__ __align__(16) short Ys[64 * 136];
  const int tid = threadIdx.x;
  const long long p0 = (long long)blockIdx.x * 64;
  const int bi = (int)(p0 >> 16);

  {
    const int tn = tid & 31, tm = tid >> 5;
    const int c4 = tn * 4;
    float4 sv = *(const float4*)(sums + bi * DM + c4);
    float4 rs;
    rs.x = 1.f / sv.x; rs.y = 1.f / sv.y; rs.z = 1.f / sv.z; rs.w = 1.f / sv.w;
#pragma unroll
    for (int pr = 0; pr < 8; ++pr) {
      int p = tm * 8 + pr;
      long long idx = (p0 + p) * DM + c4;
      ushort4 e = *(const ushort4*)(Ebf + idx);
      float4 a;
      a.x = bf2f(e.x) * rs.x; a.y = bf2f(e.y) * rs.y;
      a.z = bf2f(e.z) * rs.z; a.w = bf2f(e.w) * rs.w;
      *(float4*)(out_attn + idx) = a;
      ushort4 g = *(const ushort4*)(Gbf + idx);
      short4 y;
      y.x = (short)f2bf(a.x * bf2f(g.x)); y.y = (short)f2bf(a.y * bf2f(g.y));
      y.z = (short)f2bf(a.z * bf2f(g.z)); y.w = (short)f2bf(a.w * bf2f(g.w));
      *(short4*)(Ys + p * 136 + c4) = y;
    }
  }

  const int wid = tid >> 6, lane = tid & 63;
  const int col = lane & 15, quad = lane >> 4;
  const int n = wid * 16 + col;
  short8v bw[4];
#pragma unroll
  for (int kt = 0; kt < 4; ++kt)
    bw[kt] = *(const short8v*)(fc2t + n * DM + kt * 32 + quad * 8);
  __syncthreads();

  float4v acc[4];
#pragma unroll
  for (int mt = 0; mt < 4; ++mt)
#pragma unroll
    for (int r = 0; r < 4; ++r) acc[mt][r] = 0.f;
#pragma unroll
  for (int kt = 0; kt < 4; ++kt)
#pragma unroll
    for (int mt = 0; mt < 4; ++mt) {
      short8v a = *(const short8v*)(Ys + (mt * 16 + col) * 136 + kt * 32 + quad * 8);
      acc[mt] = __builtin_amdgcn_mfma_f32_16x16x32_bf16(a, bw[kt], acc[mt], 0, 0, 0);
    }
  float bb = fc2_b[n];
#pragma unroll
  for (int mt = 0; mt < 4; ++mt)
#pragma unroll
    for (int r = 0; r < 4; ++r) {
      long long row = p0 + mt * 16 + quad * 4 + r;
      out_res[row * DP + n] = acc[mt][r] + bb + features[row * DP + n];
    }
}

extern "C" void kernel_launch(void* const* d_in, const int* in_sizes, int n_in,
                              void* d_out, int out_size, void* d_ws, size_t ws_size,
                              hipStream_t stream) {
  const float* xyz      = (const float*)d_in[0];
  const float* features = (const float*)d_in[1];
  const float* fc1_w    = (const float*)d_in[2];
  const float* fc1_b    = (const float*)d_in[3];
  const float* fc2_w    = (const float*)d_in[4];
  const float* fc2_b    = (const float*)d_in[5];
  const float* d1_w     = (const float*)d_in[6];
  const float* d1_b     = (const float*)d_in[7];
  const float* d2_w     = (const float*)d_in[8];
  const float* d2_b     = (const float*)d_in[9];
  const float* g1_w     = (const float*)d_in[10];
  const float* g1_b     = (const float*)d_in[11];
  const float* g2_w     = (const float*)d_in[12];
  const float* g2_b     = (const float*)d_in[13];
  const float* wq       = (const float*)d_in[14];
  const float* wk       = (const float*)d_in[15];
  const float* wv       = (const float*)d_in[16];

  float* out_res  = (float*)d_out;
  float* out_attn = out_res + (long long)BB * NN * DP;

  float* sums = (float*)d_ws;                          // [256]
  short* d2t  = (short*)(sums + 256);                  // 128*128
  short* fc1t = d2t + 16384;                           // 128*64
  short* wqkt = fc1t + 8192;                           // 128*128
  short* g1t  = wqkt + 16384;
  short* g2t  = g1t + 16384;
  short* wvt  = g2t + 16384;
  short* fc2t = wvt + 16384;                           // 64*128
  unsigned short* Ebf = (unsigned short*)(fc2t + 8192);   // [BB*NN*DM] bf16 (~33.5 MB)
  unsigned short* Gbf = (unsigned short*)d_out;        // aliases res region (byte-exact)

  hipLaunchKernelGGL(k0_kernel, dim3(224), dim3(256), 0, stream,
                     wq, wk, fc1_w, fc2_w, d2_w, g1_w, g2_w, wv,
                     sums, d2t, fc1t, wqkt, g1t, g2t, wvt, fc2t);
  hipLaunchKernelGGL(k1_kernel, dim3((BB * NN) / 64), dim3(256), 0, stream,
                     xyz, features, fc1t, fc1_b, d1_w, d1_b, d2t, d2_b,
                     g1t, g1_b, g2t, g2_b, wqkt, wvt, Ebf, Gbf, sums);
  hipLaunchKernelGGL(k3_kernel, dim3((BB * NN) / 64), dim3(256), 0, stream,
                     Ebf, out_attn, out_res, Gbf, sums, fc2t, fc2_b, features);
}